// Round 3
// baseline (85.341 us; speedup 1.0000x reference)
//
#include <hip/hip_runtime.h>
#include <math.h>

// Problem: B=32, La=Lb=2048. embed_dim=1 MHA degenerates to:
//   q=a*wq+bq; k=b*wk+bk; v=b*wv+bv  (scalar affine)
//   ctx[b,i] = sum_j softmax_j(q_i*k_j) * v_j;  out = gelu_exact(ctx*ow+ob+a)
//
// dur_us is dominated by ~80us of harness 0xAA re-poison fills (268MB @ 84%
// HBM peak, top-5 rocprof slots); kernel contributes ~4-6us. R3 shaves the
// kernel's VALU floor with packed-f32 (v_pk_fma_f32: 1.5 VALU inst/exp vs 3)
// and halves LDS traffic (MI=8: one ds_read_b128 feeds 16 exps), LDS laid
// [p][split] so inner reads are lane-contiguous (conflict-free).

#define BATCH 32
#define LA 2048
#define LB 2048
#define SPLIT 32                     // threads per i-group (j-split); = chunk count
#define MI 8                         // i-values per thread (4 float2 pairs)
#define CHUNK (LB / SPLIT)           // 64 j per split-thread
#define P2 (CHUNK / 2)               // 32 kv-float4 per chunk
#define THREADS 256
#define GROUPS (THREADS / SPLIT)     // 8 i-groups per block
#define IPB (GROUPS * MI)            // 64 i per block
#define BLOCKS_PER_B (LA / IPB)      // 32
// grid = 32*32 = 1024 blocks = 4096 waves = 4 waves/SIMD

typedef float v2f __attribute__((ext_vector_type(2)));

__global__ __launch_bounds__(THREADS, 4)
void cross_attn_kernel(const float* __restrict__ a,
                       const float* __restrict__ b,
                       const float* __restrict__ w_in,
                       const float* __restrict__ b_in,
                       const float* __restrict__ w_out,
                       const float* __restrict__ b_out,
                       float* __restrict__ out)
{
    // kv2[p][split] : float4 {k(2p),v(2p),k(2p+1),v(2p+1)} for chunk `split`
    __shared__ float4 kv2[P2 * SPLIT];       // 32*32*16B = 16 KB
    __shared__ float red[8];                 // [0..3]=per-wave kmax, [4..7]=kmin

    const int tid = threadIdx.x;
    const int bb  = blockIdx.x / BLOCKS_PER_B;
    const int cc  = blockIdx.x % BLOCKS_PER_B;

    const float wq = w_in[0], wk = w_in[1], wv = w_in[2];
    const float bq = b_in[0], bk = b_in[1], bv = b_in[2];
    const float ow = w_out[0], ob = b_out[0];

    // ---- stage k,v into [p][split] LDS; track per-thread k min/max ----
    const float* brow = b + (size_t)bb * LB;
    float kmaxl = -INFINITY, kminl = INFINITY;
    {
        const int j0 = tid * 8;                        // 8 consecutive j, one chunk
        float4 b0 = *(const float4*)(brow + j0);
        float4 b1 = *(const float4*)(brow + j0 + 4);
        float bv8[8] = {b0.x, b0.y, b0.z, b0.w, b1.x, b1.y, b1.z, b1.w};
        const int c  = j0 >> 6;                        // chunk = split index (0..31)
        const int p0 = (j0 & (CHUNK - 1)) >> 1;        // first pair index
        #pragma unroll
        for (int e = 0; e < 4; ++e) {
            float k0 = fmaf(bv8[2 * e],     wk, bk);
            float v0 = fmaf(bv8[2 * e],     wv, bv);
            float k1 = fmaf(bv8[2 * e + 1], wk, bk);
            float v1 = fmaf(bv8[2 * e + 1], wv, bv);
            kv2[(p0 + e) * SPLIT + c] = make_float4(k0, v0, k1, v1);
            kmaxl = fmaxf(kmaxl, fmaxf(k0, k1));
            kminl = fminf(kminl, fminf(k0, k1));
        }
    }

    #pragma unroll
    for (int off = 1; off < 64; off <<= 1) {
        kmaxl = fmaxf(kmaxl, __shfl_xor(kmaxl, off, 64));
        kminl = fminf(kminl, __shfl_xor(kminl, off, 64));
    }
    const int lane = tid & 63, wave = tid >> 6;
    if (lane == 0) { red[wave] = kmaxl; red[4 + wave] = kminl; }
    __syncthreads();
    const float kmax = fmaxf(fmaxf(red[0], red[1]), fmaxf(red[2], red[3]));
    const float kmin = fminf(fminf(red[4], red[5]), fminf(red[6], red[7]));

    // ---- per-thread setup: MI=8 i-values (4 float2 pairs), 32-way j split ----
    const int split = tid & (SPLIT - 1);
    const int g     = tid >> 5;                        // 0..7
    const int i0    = cc * IPB + g * MI;               // multiple of 8
    const float* ap = a + (size_t)bb * LA + i0;
    float4 a0 = *(const float4*)(ap);
    float4 a1 = *(const float4*)(ap + 4);
    const float avals[MI] = {a0.x, a0.y, a0.z, a0.w, a1.x, a1.y, a1.z, a1.w};

    const float L2E = 1.4426950408889634f;
    v2f t2v[MI / 2], nm2v[MI / 2], numv[MI / 2], denv[MI / 2];
    #pragma unroll
    for (int m = 0; m < MI / 2; ++m) {
        #pragma unroll
        for (int h = 0; h < 2; ++h) {
            float t  = fmaf(avals[2 * m + h], wq, bq);
            float t2 = t * L2E;
            t2v[m][h]  = t2;
            nm2v[m][h] = -((t2 >= 0.0f) ? t2 * kmax : t2 * kmin);
        }
        numv[m] = (v2f)(0.0f);
        denv[m] = (v2f)(0.0f);
    }

    const float4* kvp = kv2 + split;                   // [p][split], stride SPLIT

    #pragma unroll 8
    for (int p = 0; p < P2; ++p) {
        const float4 q = kvp[p * SPLIT];               // lane-contiguous b128
        const v2f k0 = (v2f)(q.x), v0 = (v2f)(q.y);
        const v2f k1 = (v2f)(q.z), v1 = (v2f)(q.w);
        #pragma unroll
        for (int m = 0; m < MI / 2; ++m) {
            v2f a0v = __builtin_elementwise_fma(t2v[m], k0, nm2v[m]);  // v_pk_fma_f32
            v2f e0;
            e0.x = __builtin_amdgcn_exp2f(a0v.x);
            e0.y = __builtin_amdgcn_exp2f(a0v.y);
            numv[m] = __builtin_elementwise_fma(e0, v0, numv[m]);      // v_pk_fma_f32
            denv[m] += e0;                                             // v_pk_add_f32
            v2f a1v = __builtin_elementwise_fma(t2v[m], k1, nm2v[m]);
            v2f e1;
            e1.x = __builtin_amdgcn_exp2f(a1v.x);
            e1.y = __builtin_amdgcn_exp2f(a1v.y);
            numv[m] = __builtin_elementwise_fma(e1, v1, numv[m]);
            denv[m] += e1;
        }
    }

    // butterfly reduce across the 32 split-lanes (masks stay in 32-lane half)
    #pragma unroll
    for (int mask = 1; mask < SPLIT; mask <<= 1) {
        #pragma unroll
        for (int m = 0; m < MI / 2; ++m) {
            numv[m].x += __shfl_xor(numv[m].x, mask, 64);
            numv[m].y += __shfl_xor(numv[m].y, mask, 64);
            denv[m].x += __shfl_xor(denv[m].x, mask, 64);
            denv[m].y += __shfl_xor(denv[m].y, mask, 64);
        }
    }

    if (split == 0) {
        float res[MI];
        #pragma unroll
        for (int m = 0; m < MI; ++m) {
            float nm  = (m & 1) ? numv[m >> 1].y : numv[m >> 1].x;
            float dn  = (m & 1) ? denv[m >> 1].y : denv[m >> 1].x;
            float ctx = nm / dn;
            float x   = fmaf(ctx, ow, ob);
            float y   = x + avals[m];
            res[m] = 0.5f * y * (1.0f + erff(y * 0.70710678118654752f));
        }
        float* op = out + (size_t)bb * LA + i0;
        *(float4*)(op)     = make_float4(res[0], res[1], res[2], res[3]);
        *(float4*)(op + 4) = make_float4(res[4], res[5], res[6], res[7]);
    }
}

extern "C" void kernel_launch(void* const* d_in, const int* in_sizes, int n_in,
                              void* d_out, int out_size, void* d_ws, size_t ws_size,
                              hipStream_t stream) {
    const float* a  = (const float*)d_in[0];
    const float* b  = (const float*)d_in[1];
    const float* wi = (const float*)d_in[2];
    const float* bi = (const float*)d_in[3];
    const float* wo = (const float*)d_in[4];
    const float* bo = (const float*)d_in[5];
    float* out = (float*)d_out;

    dim3 grid(BATCH * BLOCKS_PER_B);   // 1024 blocks -> 4 waves/SIMD
    dim3 block(THREADS);
    cross_attn_kernel<<<grid, block, 0, stream>>>(a, b, wi, bi, wo, bo, out);
}